// Round 1
// baseline (162.476 us; speedup 1.0000x reference)
//
#include <hip/hip_runtime.h>

#define RREG 36
#define TTOK 64
#define DDIM 1024

typedef __attribute__((ext_vector_type(4))) float f32x4;
typedef __attribute__((ext_vector_type(8))) short bf16x8;

__device__ __forceinline__ unsigned short f2bf(float x) {
  unsigned int u = __float_as_uint(x);
  u += 0x7fffu + ((u >> 16) & 1u);   // round-to-nearest-even
  return (unsigned short)(u >> 16);
}

// LDS layout (bytes):
//   [0,17408)      scap  [64][136] bf16   (phase A)         -- aliased by:
//   [0,14336)      simgT [128][56] bf16   (phase B)
//   [17408,30464)  simg  [48][136] bf16   (phase A)
//   [32768,45440)  ssc   [48][66]  f32    (raw dots)
//   [45440,51584)  satt  [64][48]  bf16   (attn^T, cols>=36 zero)
//   [51584,51776)  sni   [48] f32  img norms
//   [51776,52032)  snc   [64] f32  cap norms
__global__ __launch_bounds__(1024) void scan_fused(
    const float* __restrict__ img, const float* __restrict__ cap,
    float* __restrict__ out) {
  __shared__ __align__(16) unsigned char smem[52032];

  unsigned short* scap  = (unsigned short*)(smem + 0);
  unsigned short* simg  = (unsigned short*)(smem + 17408);
  unsigned short* simgT = (unsigned short*)(smem + 0);
  float* ssc            = (float*)(smem + 32768);
  unsigned short* satt  = (unsigned short*)(smem + 45440);
  float* sni            = (float*)(smem + 51584);
  float* snc            = (float*)(smem + 51776);

  const int tid  = threadIdx.x;
  const int lane = tid & 63;
  const int wave = tid >> 6;
  const int fm   = lane & 15;   // m/n within a 16x16 tile
  const int kq   = lane >> 4;   // k-quad
  const int b    = blockIdx.x;

  const float* imgb = img + (size_t)b * RREG * DDIM;
  const float* capb = cap + (size_t)b * TTOK * DDIM;
  float*       outb = out + (size_t)b * TTOK * DDIM;

  const int mt = wave >> 2;     // phase A tile coords (waves 0..11): mt 0..2
  const int nt = wave & 3;      //                                    nt 0..3

  f32x4 acc = {0.f, 0.f, 0.f, 0.f};
  float cn0 = 0.f, cn1 = 0.f, in0 = 0.f, in1 = 0.f;

  const int trow = tid >> 5;    // 0..31 (row owner for staging + norms)
  const int d4   = tid & 31;    // float4 slot within 128-d chunk

  // ---------------- Phase A: dots = img(36x1024) . cap^T(1024x64) ----------------
  for (int c = 0; c < 8; ++c) {
    const int dbase = c * 128 + d4 * 4;
    // stage cap chunk (64 x 128) as bf16, accumulate fp32 norm^2 partials
    {
      float4 v = *(const float4*)(capb + trow * DDIM + dbase);
      cn0 += v.x * v.x + v.y * v.y + v.z * v.z + v.w * v.w;
      ushort4 p; p.x = f2bf(v.x); p.y = f2bf(v.y); p.z = f2bf(v.z); p.w = f2bf(v.w);
      *(ushort4*)(scap + trow * 136 + d4 * 4) = p;

      float4 w = *(const float4*)(capb + (trow + 32) * DDIM + dbase);
      cn1 += w.x * w.x + w.y * w.y + w.z * w.z + w.w * w.w;
      ushort4 q; q.x = f2bf(w.x); q.y = f2bf(w.y); q.z = f2bf(w.z); q.w = f2bf(w.w);
      *(ushort4*)(scap + (trow + 32) * 136 + d4 * 4) = q;
    }
    // stage img chunk (48 x 128; rows >= 36 zeroed)
    {
      float4 v = *(const float4*)(imgb + trow * DDIM + dbase);
      in0 += v.x * v.x + v.y * v.y + v.z * v.z + v.w * v.w;
      ushort4 p; p.x = f2bf(v.x); p.y = f2bf(v.y); p.z = f2bf(v.z); p.w = f2bf(v.w);
      *(ushort4*)(simg + trow * 136 + d4 * 4) = p;
      if (tid < 512) {
        int r2 = trow + 32;      // 32..47
        float4 w = make_float4(0.f, 0.f, 0.f, 0.f);
        if (r2 < RREG) {
          w = *(const float4*)(imgb + r2 * DDIM + dbase);
          in1 += w.x * w.x + w.y * w.y + w.z * w.z + w.w * w.w;
        }
        ushort4 q; q.x = f2bf(w.x); q.y = f2bf(w.y); q.z = f2bf(w.z); q.w = f2bf(w.w);
        *(ushort4*)(simg + r2 * 136 + d4 * 4) = q;
      }
    }
    __syncthreads();
    if (wave < 12) {
      // A-frag: A[m=r][k=d] from simg row; B-frag: B[k=d][n=t] from scap row (k-contiguous)
      const unsigned short* arow = simg + (mt * 16 + fm) * 136 + kq * 8;
      const unsigned short* brow = scap + (nt * 16 + fm) * 136 + kq * 8;
#pragma unroll
      for (int ks = 0; ks < 4; ++ks) {
        bf16x8 av = *(const bf16x8*)(arow + ks * 32);
        bf16x8 bv = *(const bf16x8*)(brow + ks * 32);
        acc = __builtin_amdgcn_mfma_f32_16x16x32_bf16(av, bv, acc, 0, 0, 0);
      }
    }
    __syncthreads();
  }

  // dump raw dots: D row=(kq*4+i), col=fm  ->  ssc[r][t]
  if (wave < 12) {
#pragma unroll
    for (int i = 0; i < 4; ++i)
      ssc[(mt * 16 + kq * 4 + i) * 66 + nt * 16 + fm] = acc[i];
  }
  // norm reductions across 32-thread row groups
#pragma unroll
  for (int off = 16; off > 0; off >>= 1) {
    cn0 += __shfl_down(cn0, off, 32);
    cn1 += __shfl_down(cn1, off, 32);
    in0 += __shfl_down(in0, off, 32);
    in1 += __shfl_down(in1, off, 32);
  }
  if ((tid & 31) == 0) {
    snc[trow]      = sqrtf(cn0);
    snc[trow + 32] = sqrtf(cn1);
    sni[trow]      = sqrtf(in0);
    if (trow < 16) sni[trow + 32] = sqrtf(in1);
  }
  __syncthreads();

  // ---------------- softmax over r, per t (wave 0; lane = t) ----------------
  if (wave == 0) {
    float cn = snc[lane];
    float s[RREG];
    float mx = -1e30f;
#pragma unroll
    for (int r = 0; r < RREG; ++r) {
      float denom = fmaxf(sni[r] * cn, 1e-8f);
      float v = ssc[r * 66 + lane] / denom;
      s[r] = v;
      mx = fmaxf(mx, v);
    }
    float sum = 0.f;
#pragma unroll
    for (int r = 0; r < RREG; ++r) { float e = __expf(s[r] - mx); s[r] = e; sum += e; }
    float rinv = 1.f / sum;
    unsigned short* ap = satt + lane * 48;
#pragma unroll
    for (int r = 0; r < RREG; ++r) ap[r] = f2bf(s[r] * rinv);
#pragma unroll
    for (int r = RREG; r < 48; ++r) ap[r] = 0;
  }
  __syncthreads();

  // ---------------- Phase B: out = attn^T(64x36) . img(36x1024) ----------------
  const int mtB = wave >> 2;   // t-tile 0..3 (4 waves each)
  const unsigned short* arowB = satt + (mtB * 16 + fm) * 48;
  bf16x8 a1 = *(const bf16x8*)(arowB + kq * 8);            // k = 0..31
  bf16x8 a2 = {0, 0, 0, 0, 0, 0, 0, 0};                    // k = 32..47 (48..63 zero)
  if (kq < 2) a2 = *(const bf16x8*)(arowB + 32 + kq * 8);

  for (int cb = 0; cb < 8; ++cb) {
    __syncthreads();   // previous chunk's reads done before overwriting simgT
    // stage img transposed: simgT[d][r], rows r>=36 zero
    for (int f = tid; f < 1536; f += 1024) {
      int g = f & 511;
      int r = (f >> 9) * 16 + (g & 15);
      int qd = (g >> 4) & 3;
      int sd = g >> 6;                    // 0..7
      int dloc = (qd + 4 * sd) * 4;       // 0..124 step 4
      float4 v = make_float4(0.f, 0.f, 0.f, 0.f);
      if (r < RREG) v = *(const float4*)(imgb + r * DDIM + cb * 128 + dloc);
      simgT[(dloc + 0) * 56 + r] = f2bf(v.x);
      simgT[(dloc + 1) * 56 + r] = f2bf(v.y);
      simgT[(dloc + 2) * 56 + r] = f2bf(v.z);
      simgT[(dloc + 3) * 56 + r] = f2bf(v.w);
    }
    __syncthreads();
#pragma unroll
    for (int j = 0; j < 2; ++j) {
      int ntB = (wave & 3) * 2 + j;       // d-tile within chunk: 0..7
      const unsigned short* brow = simgT + (ntB * 16 + fm) * 56;
      bf16x8 b1 = *(const bf16x8*)(brow + kq * 8);
      bf16x8 b2 = {0, 0, 0, 0, 0, 0, 0, 0};
      if (kq < 2) b2 = *(const bf16x8*)(brow + 32 + kq * 8);
      f32x4 o = {0.f, 0.f, 0.f, 0.f};
      o = __builtin_amdgcn_mfma_f32_16x16x32_bf16(a1, b1, o, 0, 0, 0);
      o = __builtin_amdgcn_mfma_f32_16x16x32_bf16(a2, b2, o, 0, 0, 0);
#pragma unroll
      for (int i = 0; i < 4; ++i)
        outb[(mtB * 16 + kq * 4 + i) * DDIM + cb * 128 + ntB * 16 + fm] = o[i];
    }
  }
}

extern "C" void kernel_launch(void* const* d_in, const int* in_sizes, int n_in,
                              void* d_out, int out_size, void* d_ws, size_t ws_size,
                              hipStream_t stream) {
  const float* img = (const float*)d_in[0];   // (256, 36, 1024) fp32
  const float* cap = (const float*)d_in[1];   // (256, 64, 1024) fp32
  // d_in[2] = cap_mask, unused by reference forward
  float* out = (float*)d_out;                 // (256, 64, 1024) fp32
  scan_fused<<<dim3(256), dim3(1024), 0, stream>>>(img, cap, out);
}